// Round 8
// baseline (187.947 us; speedup 1.0000x reference)
//
#include <hip/hip_runtime.h>

#define EDIM 128
#define MDIM 8
#define ADIM 64
#define NFR  50
#define NCOL (NFR * MDIM)   // 400
#define NPART 64            // k2a blocks

typedef __attribute__((ext_vector_type(8))) short short8;
typedef __attribute__((ext_vector_type(4))) float f32x4;

__device__ __forceinline__ float waveReduceSum(float v) {
    #pragma unroll
    for (int s = 32; s >= 1; s >>= 1) v += __shfl_xor(v, s, 64);
    return v;
}
__device__ __forceinline__ short f2bf(float x) {
    unsigned u = __float_as_uint(x);
    u += 0x7FFFu + ((u >> 16) & 1u);
    return (short)(u >> 16);
}
__device__ __forceinline__ float bf2f(short s) {
    return __uint_as_float(((unsigned)(unsigned short)s) << 16);
}

// k0: prepack static A-fragments + zero S accumulator
__global__ __launch_bounds__(256)
void k0_prep(const float* __restrict__ WA, const float* __restrict__ Mem,
             const float* __restrict__ Key,
             short* __restrict__ WATf, short* __restrict__ MemTf,
             short* __restrict__ KeyTf, float* __restrict__ S)
{
    int t = blockIdx.x * 256 + threadIdx.x;
    int lane = t & 63, c = lane & 15, g = (lane >> 4) & 3;
    short8 v = {0, 0, 0, 0, 0, 0, 0, 0};
    if (t < 1024) {                       // WATf: frag = Ma*4+Kt
        int frag = t >> 6, Ma = frag >> 2, Kt = frag & 3;
        int a = Ma * 16 + c;
        #pragma unroll
        for (int j = 0; j < 8; ++j) {
            int e = Kt * 32 + g * 8 + j;
            v[j] = f2bf(WA[(size_t)e * ADIM + a]);
        }
        *(short8*)(WATf + (size_t)t * 8) = v;
    } else if (t < 1536) {                // MemTf
        int i = t - 1024, Mt = i >> 6;
        int e = Mt * 16 + c;
        #pragma unroll
        for (int j = 0; j < 8; ++j) {
            int k = g * 8 + j;
            v[j] = (k < MDIM) ? f2bf(Mem[(size_t)k * EDIM + e]) : (short)0;
        }
        *(short8*)(MemTf + (size_t)i * 8) = v;
    } else if (t < 1792) {                // KeyTf
        int i = t - 1536, Kt = i >> 6;
        #pragma unroll
        for (int j = 0; j < 8; ++j) {
            int e = Kt * 32 + g * 8 + j;
            v[j] = (c < MDIM) ? f2bf(Key[(size_t)e * MDIM + c]) : (short)0;
        }
        *(short8*)(KeyTf + (size_t)i * 8) = v;
    } else if (t < 1792 + NCOL) {         // zero S
        S[t - 1792] = 0.f;
    }
}

// k1: eatt = exp(att_key) via MFMA; ALSO writes fe*fn (bf16, row-major) to feB
// so k3 never re-gathers. |att_key| <= 0.1 by Cauchy-Schwarz -> no max needed.
__global__ __launch_bounds__(256, 6)
void k1_attkey(const int* __restrict__ input_u, const int* __restrict__ input_uf,
               const float* __restrict__ uidW, const short* __restrict__ KeyTf,
               float* __restrict__ eatt, short* __restrict__ feB, int user_num)
{
    const int b = blockIdx.x, t = threadIdx.x, w = t >> 6, l = t & 63;
    const int c = l & 15, g = l >> 4;
    __shared__ float uidn[EDIM];
    __shared__ float redW[4];
    __shared__ int ufL[64];

    if (t < 64) ufL[t] = (t < NFR) ? input_uf[(size_t)b * NFR + t] : user_num;
    const int u = input_u[b];
    float x = (t < EDIM) ? uidW[(size_t)u * EDIM + t] : 0.f;
    float ss = waveReduceSum(x * x);
    if (l == 0) redW[w] = ss;
    __syncthreads();
    float uinv = 1.0f / fmaxf(sqrtf(redW[0] + redW[1] + redW[2] + redW[3]), 1e-12f);
    if (t < EDIM) uidn[t] = x * uinv;
    __syncthreads();

    const int f = w * 16 + c;
    const int fid = ufL[f];
    const float fn = (f < NFR && fid != user_num) ? 1.0f : 0.0f;
    const float* fp = uidW + (size_t)fid * EDIM;

    float4 fe[4][2];
    #pragma unroll
    for (int Kt = 0; Kt < 4; ++Kt) {
        fe[Kt][0] = *(const float4*)(fp + Kt * 32 + g * 8);
        fe[Kt][1] = *(const float4*)(fp + Kt * 32 + g * 8 + 4);
    }
    float fss = 0.f;
    #pragma unroll
    for (int Kt = 0; Kt < 4; ++Kt)
        #pragma unroll
        for (int h = 0; h < 2; ++h) {
            float4 q = fe[Kt][h];
            fss += q.x * q.x + q.y * q.y + q.z * q.z + q.w * q.w;
        }
    fss += __shfl_xor(fss, 16, 64);
    fss += __shfl_xor(fss, 32, 64);
    const float inv2 = fn / fmaxf(sqrtf(fss), 1e-12f);

    short* fbb = feB + (size_t)b * 8192;   // [f][e] row-major bf16
    f32x4 acc = {0.f, 0.f, 0.f, 0.f};
    #pragma unroll
    for (int Kt = 0; Kt < 4; ++Kt) {
        // write fe*fn (bf16) — one 16-B store per Kt
        short8 fo;
        fo[0] = f2bf(fe[Kt][0].x * fn); fo[1] = f2bf(fe[Kt][0].y * fn);
        fo[2] = f2bf(fe[Kt][0].z * fn); fo[3] = f2bf(fe[Kt][0].w * fn);
        fo[4] = f2bf(fe[Kt][1].x * fn); fo[5] = f2bf(fe[Kt][1].y * fn);
        fo[6] = f2bf(fe[Kt][1].z * fn); fo[7] = f2bf(fe[Kt][1].w * fn);
        *(short8*)(fbb + f * 128 + Kt * 32 + g * 8) = fo;

        float4 un0 = *(const float4*)&uidn[Kt * 32 + g * 8];
        float4 un1 = *(const float4*)&uidn[Kt * 32 + g * 8 + 4];
        short8 bf;
        bf[0] = f2bf(un0.x * fe[Kt][0].x * inv2);
        bf[1] = f2bf(un0.y * fe[Kt][0].y * inv2);
        bf[2] = f2bf(un0.z * fe[Kt][0].z * inv2);
        bf[3] = f2bf(un0.w * fe[Kt][0].w * inv2);
        bf[4] = f2bf(un1.x * fe[Kt][1].x * inv2);
        bf[5] = f2bf(un1.y * fe[Kt][1].y * inv2);
        bf[6] = f2bf(un1.z * fe[Kt][1].z * inv2);
        bf[7] = f2bf(un1.w * fe[Kt][1].w * inv2);
        short8 af = *(const short8*)(KeyTf + (size_t)(Kt * 64 + l) * 8);
        acc = __builtin_amdgcn_mfma_f32_16x16x32_bf16(af, bf, acc, 0, 0, 0);
    }
    if (f < NFR && g < 2) {
        float4 st = {__expf(acc[0]), __expf(acc[1]), __expf(acc[2]), __expf(acc[3])};
        *(float4*)&eatt[(size_t)b * NCOL + f * MDIM + g * 4] = st;
    }
}

// k2a: row-coalesced partial column sums, atomicAdd into S[400]
__global__ __launch_bounds__(256)
void k2a_sum(const float* __restrict__ eatt, float* __restrict__ S, int B)
{
    const int blk = blockIdx.x, t = threadIdx.x, w = t >> 6, l = t & 63;
    __shared__ float colS[4][NCOL];
    const int rowsPerBlk = B / NPART;          // 64
    const int rowsPerWave = rowsPerBlk >> 2;   // 16
    const int r0 = blk * rowsPerBlk + w * rowsPerWave;

    float4 a1 = {0.f, 0.f, 0.f, 0.f}, a2 = {0.f, 0.f, 0.f, 0.f};
    for (int it = 0; it < rowsPerWave; ++it) {
        const float* row = eatt + (size_t)(r0 + it) * NCOL;
        float4 v1 = *(const float4*)(row + 4 * l);
        a1.x += v1.x; a1.y += v1.y; a1.z += v1.z; a1.w += v1.w;
        if (l < 36) {
            float4 v2 = *(const float4*)(row + 256 + 4 * l);
            a2.x += v2.x; a2.y += v2.y; a2.z += v2.z; a2.w += v2.w;
        }
    }
    *(float4*)&colS[w][4 * l] = a1;
    if (l < 36) *(float4*)&colS[w][256 + 4 * l] = a2;
    __syncthreads();
    for (int i = t; i < NCOL; i += 256)
        atomicAdd(&S[i], colS[0][i] + colS[1][i] + colS[2][i] + colS[3][i]);
}

// k3: am from eatt*rcp(S) -> f1^T MFMA -> f2 (feB coalesced) -> h^T MFMA
//     (+iid row tile => y_f) -> p fold -> j -> score
__global__ __launch_bounds__(256, 6)
void k3_final(const int* __restrict__ input_u, const int* __restrict__ input_i,
              const int* __restrict__ input_uf, const float* __restrict__ uidW,
              const float* __restrict__ iidW, const float* __restrict__ i_bias,
              const short* __restrict__ WATf, const short* __restrict__ MemTf,
              const float* __restrict__ BA, const float* __restrict__ U_omega,
              const float* __restrict__ eatt, const float* __restrict__ S,
              const short* __restrict__ feB, float* __restrict__ out,
              int user_num)
{
    const int b = blockIdx.x, t = threadIdx.x, w = t >> 6, l = t & 63;
    const int c = l & 15, g = l >> 4;
    __shared__ short f2s[4][4 * 64 * 8];  // 16 KB per-wave B-frag staging
    __shared__ float uidL[EDIM], iidL[EDIM];
    __shared__ float baL[ADIM], uoL[ADIM];
    __shared__ int ufL[64];
    __shared__ float sjW[4], syW[4];

    if (t < 64) ufL[t] = (t < NFR) ? input_uf[(size_t)b * NFR + t] : user_num;
    const int u = input_u[b];
    const int ii = input_i[b];
    if (t < EDIM) {
        uidL[t] = uidW[(size_t)u * EDIM + t];
        iidL[t] = iidW[(size_t)ii * EDIM + t];
    }
    if (t < ADIM) { baL[t] = BA[t]; uoL[t] = U_omega[t]; }
    __syncthreads();

    const int f = w * 16 + c;
    const float fn = (f < NFR && ufL[f] != user_num) ? 1.0f : 0.0f;
    const short* fbb = feB + (size_t)b * 8192;

    // am B-frag: only g==0 lanes carry data (k in [0,8) = m)
    short8 amf = {0, 0, 0, 0, 0, 0, 0, 0};
    if (g == 0 && fn > 0.f) {
        const float* ea = eatt + (size_t)b * NCOL + f * 8;
        float4 e0 = *(const float4*)ea;
        float4 e1 = *(const float4*)(ea + 4);
        float4 s0 = *(const float4*)&S[f * 8];
        float4 s1 = *(const float4*)&S[f * 8 + 4];
        amf[0] = f2bf(e0.x * __builtin_amdgcn_rcpf(s0.x));
        amf[1] = f2bf(e0.y * __builtin_amdgcn_rcpf(s0.y));
        amf[2] = f2bf(e0.z * __builtin_amdgcn_rcpf(s0.z));
        amf[3] = f2bf(e0.w * __builtin_amdgcn_rcpf(s0.w));
        amf[4] = f2bf(e1.x * __builtin_amdgcn_rcpf(s1.x));
        amf[5] = f2bf(e1.y * __builtin_amdgcn_rcpf(s1.y));
        amf[6] = f2bf(e1.z * __builtin_amdgcn_rcpf(s1.z));
        amf[7] = f2bf(e1.w * __builtin_amdgcn_rcpf(s1.w));
    }

    // f1^T = Mem^T x am^T
    f32x4 C1[8];
    #pragma unroll
    for (int Mt = 0; Mt < 8; ++Mt) {
        short8 af = *(const short8*)(MemTf + (size_t)(Mt * 64 + l) * 8);
        f32x4 z = {0.f, 0.f, 0.f, 0.f};
        C1[Mt] = __builtin_amdgcn_mfma_f32_16x16x32_bf16(af, amf, z, 0, 0, 0);
    }

    // f2 = f1 * fe (fe from feB, coalesced; fn already baked into feB)
    #pragma unroll
    for (int Mt = 0; Mt < 8; ++Mt) {
        uint2 fv = *(const uint2*)(fbb + f * 128 + Mt * 16 + g * 4);
        float q0 = C1[Mt][0] * bf2f((short)(fv.x & 0xFFFF));
        float q1 = C1[Mt][1] * bf2f((short)(fv.x >> 16));
        float q2 = C1[Mt][2] * bf2f((short)(fv.y & 0xFFFF));
        float q3 = C1[Mt][3] * bf2f((short)(fv.y >> 16));
        unsigned d0 = ((unsigned)(unsigned short)f2bf(q0)) |
                      (((unsigned)(unsigned short)f2bf(q1)) << 16);
        unsigned d1 = ((unsigned)(unsigned short)f2bf(q2)) |
                      (((unsigned)(unsigned short)f2bf(q3)) << 16);
        int lane2 = ((Mt & 1) * 2 + (g >> 1)) * 16 + c;
        int off = ((Mt >> 1) * 64 + lane2) * 8 + (g & 1) * 4;
        uint2 dd = {d0, d1};
        *(uint2*)&f2s[w][off] = dd;
    }

    // h^T = WA^T x f2^T (+ iid row tile => y_f)
    f32x4 C2[4], C3 = {0.f, 0.f, 0.f, 0.f};
    #pragma unroll
    for (int Ma = 0; Ma < 4; ++Ma) C2[Ma] = (f32x4){0.f, 0.f, 0.f, 0.f};
    #pragma unroll
    for (int Kt = 0; Kt < 4; ++Kt) {
        short8 bf = *(const short8*)&f2s[w][(Kt * 64 + l) * 8];
        #pragma unroll
        for (int Ma = 0; Ma < 4; ++Ma) {
            short8 af = *(const short8*)(WATf + (size_t)((Ma * 4 + Kt) * 64 + l) * 8);
            C2[Ma] = __builtin_amdgcn_mfma_f32_16x16x32_bf16(af, bf, C2[Ma], 0, 0, 0);
        }
        short8 itf = {0, 0, 0, 0, 0, 0, 0, 0};
        if (c == 0) {
            float4 i0 = *(const float4*)&iidL[Kt * 32 + g * 8];
            float4 i1 = *(const float4*)&iidL[Kt * 32 + g * 8 + 4];
            itf[0] = f2bf(i0.x); itf[1] = f2bf(i0.y);
            itf[2] = f2bf(i0.z); itf[3] = f2bf(i0.w);
            itf[4] = f2bf(i1.x); itf[5] = f2bf(i1.y);
            itf[6] = f2bf(i1.z); itf[7] = f2bf(i1.w);
        }
        C3 = __builtin_amdgcn_mfma_f32_16x16x32_bf16(itf, bf, C3, 0, 0, 0);
    }

    float psum = 0.f;
    #pragma unroll
    for (int Ma = 0; Ma < 4; ++Ma) {
        float4 ba4 = *(const float4*)&baL[Ma * 16 + g * 4];
        float4 uo4 = *(const float4*)&uoL[Ma * 16 + g * 4];
        psum += fmaxf(C2[Ma][0] + ba4.x, 0.f) * uo4.x;
        psum += fmaxf(C2[Ma][1] + ba4.y, 0.f) * uo4.y;
        psum += fmaxf(C2[Ma][2] + ba4.z, 0.f) * uo4.z;
        psum += fmaxf(C2[Ma][3] + ba4.w, 0.f) * uo4.w;
    }
    psum += __shfl_xor(psum, 16, 64);
    psum += __shfl_xor(psum, 32, 64);
    const float jv = (fn > 0.f) ? __expf(psum) : 0.f;
    const float jy = jv * C3[0];
    float sj = waveReduceSum((g == 0) ? jv : 0.f);
    float sy = waveReduceSum(jy);
    if (l == 0) { sjW[w] = sj; syW[w] = sy; }
    __syncthreads();

    if (w == 0) {
        float s = uidL[l] * iidL[l] + uidL[l + 64] * iidL[l + 64];
        s = waveReduceSum(s);
        if (l == 0) {
            float Sj = sjW[0] + sjW[1] + sjW[2] + sjW[3] + 1e-8f;
            float Sy = syW[0] + syW[1] + syW[2] + syW[3];
            out[b] = s + Sy / Sj + i_bias[ii];
        }
    }
}

extern "C" void kernel_launch(void* const* d_in, const int* in_sizes, int n_in,
                              void* d_out, int out_size, void* d_ws, size_t ws_size,
                              hipStream_t stream)
{
    const int*   input_u  = (const int*)d_in[0];
    const int*   input_i  = (const int*)d_in[1];
    const int*   input_uf = (const int*)d_in[2];
    const float* uidW     = (const float*)d_in[3];
    const float* iidW     = (const float*)d_in[4];
    const float* i_bias   = (const float*)d_in[5];
    const float* Key      = (const float*)d_in[6];
    const float* Mem      = (const float*)d_in[7];
    const float* WA       = (const float*)d_in[8];
    const float* BA       = (const float*)d_in[9];
    const float* U_om     = (const float*)d_in[10];

    const int B = in_sizes[0];
    const int user_num = in_sizes[3] / EDIM - 1;

    float* eatt = (float*)d_ws;                      // B*400 floats
    float* S    = eatt + (size_t)B * NCOL;           // 400 floats
    short* WATf  = (short*)(S + NCOL);               // 16*64*8
    short* MemTf = WATf + 16 * 64 * 8;               // 8*64*8
    short* KeyTf = MemTf + 8 * 64 * 8;               // 4*64*8
    short* feB   = KeyTf + 4 * 64 * 8;               // B*8192 shorts (67 MB)

    k0_prep<<<9, 256, 0, stream>>>(WA, Mem, Key, WATf, MemTf, KeyTf, S);
    k1_attkey<<<B, 256, 0, stream>>>(input_u, input_uf, uidW, KeyTf, eatt, feB, user_num);
    k2a_sum<<<NPART, 256, 0, stream>>>(eatt, S, B);
    k3_final<<<B, 256, 0, stream>>>(input_u, input_i, input_uf, uidW, iidW, i_bias,
                                    WATf, MemTf, BA, U_om, eatt, S, feB,
                                    (float*)d_out, user_num);
}

// Round 9
// 173.754 us; speedup vs baseline: 1.0817x; 1.0817x over previous
//
#include <hip/hip_runtime.h>

#define EDIM 128
#define MDIM 8
#define ADIM 64
#define NFR  50
#define NCOL (NFR * MDIM)   // 400
#define NPART 64            // k2a blocks

typedef __attribute__((ext_vector_type(8))) short short8;
typedef __attribute__((ext_vector_type(4))) float f32x4;

__device__ __forceinline__ float waveReduceSum(float v) {
    #pragma unroll
    for (int s = 32; s >= 1; s >>= 1) v += __shfl_xor(v, s, 64);
    return v;
}
__device__ __forceinline__ short f2bf(float x) {
    unsigned u = __float_as_uint(x);
    u += 0x7FFFu + ((u >> 16) & 1u);
    return (short)(u >> 16);
}
__device__ __forceinline__ float bf2f(short s) {
    return __uint_as_float(((unsigned)(unsigned short)s) << 16);
}

// k0_all: (a) convert uidW -> bf16 copy ubW (halves all gather rows);
//         (b) prepack static A-fragments; (c) zero S.
__global__ __launch_bounds__(256)
void k0_all(const float* __restrict__ uidW, const float* __restrict__ WA,
            const float* __restrict__ Mem, const float* __restrict__ Key,
            short* __restrict__ ubW, short* __restrict__ WATf,
            short* __restrict__ MemTf, short* __restrict__ KeyTf,
            float* __restrict__ S, int nU, int cvtBlocks)
{
    int blk = blockIdx.x;
    if (blk < cvtBlocks) {
        int idx = (blk * 256 + threadIdx.x) * 8;
        if (idx < nU) {
            float4 a = *(const float4*)(uidW + idx);
            float4 b = *(const float4*)(uidW + idx + 4);
            short8 v;
            v[0] = f2bf(a.x); v[1] = f2bf(a.y); v[2] = f2bf(a.z); v[3] = f2bf(a.w);
            v[4] = f2bf(b.x); v[5] = f2bf(b.y); v[6] = f2bf(b.z); v[7] = f2bf(b.w);
            *(short8*)(ubW + idx) = v;
        }
        return;
    }
    int t = (blk - cvtBlocks) * 256 + threadIdx.x;
    int lane = t & 63, c = lane & 15, g = (lane >> 4) & 3;
    short8 v = {0, 0, 0, 0, 0, 0, 0, 0};
    if (t < 1024) {                       // WATf: frag = Ma*4+Kt
        int frag = t >> 6, Ma = frag >> 2, Kt = frag & 3;
        int a = Ma * 16 + c;
        #pragma unroll
        for (int j = 0; j < 8; ++j) {
            int e = Kt * 32 + g * 8 + j;
            v[j] = f2bf(WA[(size_t)e * ADIM + a]);
        }
        *(short8*)(WATf + (size_t)t * 8) = v;
    } else if (t < 1536) {                // MemTf
        int i = t - 1024, Mt = i >> 6;
        int e = Mt * 16 + c;
        #pragma unroll
        for (int j = 0; j < 8; ++j) {
            int k = g * 8 + j;
            v[j] = (k < MDIM) ? f2bf(Mem[(size_t)k * EDIM + e]) : (short)0;
        }
        *(short8*)(MemTf + (size_t)i * 8) = v;
    } else if (t < 1792) {                // KeyTf
        int i = t - 1536, Kt = i >> 6;
        #pragma unroll
        for (int j = 0; j < 8; ++j) {
            int e = Kt * 32 + g * 8 + j;
            v[j] = (c < MDIM) ? f2bf(Key[(size_t)e * MDIM + c]) : (short)0;
        }
        *(short8*)(KeyTf + (size_t)i * 8) = v;
    } else if (t < 1792 + NCOL) {         // zero S
        S[t - 1792] = 0.f;
    }
}

// k1: eatt = exp(att_key) via MFMA; fe gathered as bf16 from ubW (256-B rows).
// |att_key| <= 0.1 by Cauchy-Schwarz -> no softmax max pass needed.
__global__ __launch_bounds__(256, 8)
void k1_attkey(const int* __restrict__ input_u, const int* __restrict__ input_uf,
               const short* __restrict__ ubW, const short* __restrict__ KeyTf,
               float* __restrict__ eatt, int user_num)
{
    const int b = blockIdx.x, t = threadIdx.x, w = t >> 6, l = t & 63;
    const int c = l & 15, g = l >> 4;
    __shared__ float uidn[EDIM];
    __shared__ float redW[4];
    __shared__ int ufL[64];

    if (t < 64) ufL[t] = (t < NFR) ? input_uf[(size_t)b * NFR + t] : user_num;
    const int u = input_u[b];
    float x = (t < EDIM) ? bf2f(ubW[(size_t)u * EDIM + t]) : 0.f;
    float ss = waveReduceSum(x * x);
    if (l == 0) redW[w] = ss;
    __syncthreads();
    float uinv = 1.0f / fmaxf(sqrtf(redW[0] + redW[1] + redW[2] + redW[3]), 1e-12f);
    if (t < EDIM) uidn[t] = x * uinv;
    __syncthreads();

    const int f = w * 16 + c;
    const int fid = ufL[f];
    const float fn = (f < NFR && fid != user_num) ? 1.0f : 0.0f;
    const short* fp = ubW + (size_t)fid * EDIM;

    short8 feb[4];
    #pragma unroll
    for (int Kt = 0; Kt < 4; ++Kt)
        feb[Kt] = *(const short8*)(fp + Kt * 32 + g * 8);

    float fef[4][8];
    float fss = 0.f;
    #pragma unroll
    for (int Kt = 0; Kt < 4; ++Kt)
        #pragma unroll
        for (int j = 0; j < 8; ++j) {
            float q = bf2f(feb[Kt][j]);
            fef[Kt][j] = q;
            fss += q * q;
        }
    fss += __shfl_xor(fss, 16, 64);
    fss += __shfl_xor(fss, 32, 64);
    const float inv2 = fn / fmaxf(sqrtf(fss), 1e-12f);

    f32x4 acc = {0.f, 0.f, 0.f, 0.f};
    #pragma unroll
    for (int Kt = 0; Kt < 4; ++Kt) {
        const float* un = &uidn[Kt * 32 + g * 8];
        short8 bf;
        #pragma unroll
        for (int j = 0; j < 8; ++j)
            bf[j] = f2bf(un[j] * fef[Kt][j] * inv2);
        short8 af = *(const short8*)(KeyTf + (size_t)(Kt * 64 + l) * 8);
        acc = __builtin_amdgcn_mfma_f32_16x16x32_bf16(af, bf, acc, 0, 0, 0);
    }
    if (f < NFR && g < 2) {
        float4 st = {__expf(acc[0]), __expf(acc[1]), __expf(acc[2]), __expf(acc[3])};
        *(float4*)&eatt[(size_t)b * NCOL + f * MDIM + g * 4] = st;
    }
}

// k2a: row-coalesced partial column sums, atomicAdd into S[400]
__global__ __launch_bounds__(256)
void k2a_sum(const float* __restrict__ eatt, float* __restrict__ S, int B)
{
    const int blk = blockIdx.x, t = threadIdx.x, w = t >> 6, l = t & 63;
    __shared__ float colS[4][NCOL];
    const int rowsPerBlk = B / NPART;          // 64
    const int rowsPerWave = rowsPerBlk >> 2;   // 16
    const int r0 = blk * rowsPerBlk + w * rowsPerWave;

    float4 a1 = {0.f, 0.f, 0.f, 0.f}, a2 = {0.f, 0.f, 0.f, 0.f};
    for (int it = 0; it < rowsPerWave; ++it) {
        const float* row = eatt + (size_t)(r0 + it) * NCOL;
        float4 v1 = *(const float4*)(row + 4 * l);
        a1.x += v1.x; a1.y += v1.y; a1.z += v1.z; a1.w += v1.w;
        if (l < 36) {
            float4 v2 = *(const float4*)(row + 256 + 4 * l);
            a2.x += v2.x; a2.y += v2.y; a2.z += v2.z; a2.w += v2.w;
        }
    }
    *(float4*)&colS[w][4 * l] = a1;
    if (l < 36) *(float4*)&colS[w][256 + 4 * l] = a2;
    __syncthreads();
    for (int i = t; i < NCOL; i += 256)
        atomicAdd(&S[i], colS[0][i] + colS[1][i] + colS[2][i] + colS[3][i]);
}

// k3: am from eatt*rcp(S) -> f1^T MFMA -> f2 (fe gathered bf16 from ubW) ->
//     h^T MFMA (+iid row tile => y_f) -> p fold -> j -> score
__global__ __launch_bounds__(256, 6)
void k3_final(const int* __restrict__ input_u, const int* __restrict__ input_i,
              const int* __restrict__ input_uf, const float* __restrict__ uidW,
              const float* __restrict__ iidW, const float* __restrict__ i_bias,
              const short* __restrict__ WATf, const short* __restrict__ MemTf,
              const float* __restrict__ BA, const float* __restrict__ U_omega,
              const float* __restrict__ eatt, const float* __restrict__ S,
              const short* __restrict__ ubW, float* __restrict__ out,
              int user_num)
{
    const int b = blockIdx.x, t = threadIdx.x, w = t >> 6, l = t & 63;
    const int c = l & 15, g = l >> 4;
    __shared__ short f2s[4][4 * 64 * 8];  // 16 KB per-wave B-frag staging
    __shared__ float uidL[EDIM], iidL[EDIM];
    __shared__ float baL[ADIM], uoL[ADIM];
    __shared__ int ufL[64];
    __shared__ float sjW[4], syW[4];

    if (t < 64) ufL[t] = (t < NFR) ? input_uf[(size_t)b * NFR + t] : user_num;
    const int u = input_u[b];
    const int ii = input_i[b];
    if (t < EDIM) {
        uidL[t] = uidW[(size_t)u * EDIM + t];   // fp32: score-critical
        iidL[t] = iidW[(size_t)ii * EDIM + t];
    }
    if (t < ADIM) { baL[t] = BA[t]; uoL[t] = U_omega[t]; }
    __syncthreads();

    const int f = w * 16 + c;
    const int fid = ufL[f];
    const float fn = (f < NFR && fid != user_num) ? 1.0f : 0.0f;
    const short* fp3 = ubW + (size_t)fid * EDIM;

    // am B-frag: only g==0 lanes carry data (k in [0,8) = m); fn mask here
    // zeroes C1 for invalid friends, so fe needs no mask downstream.
    short8 amf = {0, 0, 0, 0, 0, 0, 0, 0};
    if (g == 0 && fn > 0.f) {
        const float* ea = eatt + (size_t)b * NCOL + f * 8;
        float4 e0 = *(const float4*)ea;
        float4 e1 = *(const float4*)(ea + 4);
        float4 s0 = *(const float4*)&S[f * 8];
        float4 s1 = *(const float4*)&S[f * 8 + 4];
        amf[0] = f2bf(e0.x * __builtin_amdgcn_rcpf(s0.x));
        amf[1] = f2bf(e0.y * __builtin_amdgcn_rcpf(s0.y));
        amf[2] = f2bf(e0.z * __builtin_amdgcn_rcpf(s0.z));
        amf[3] = f2bf(e0.w * __builtin_amdgcn_rcpf(s0.w));
        amf[4] = f2bf(e1.x * __builtin_amdgcn_rcpf(s1.x));
        amf[5] = f2bf(e1.y * __builtin_amdgcn_rcpf(s1.y));
        amf[6] = f2bf(e1.z * __builtin_amdgcn_rcpf(s1.z));
        amf[7] = f2bf(e1.w * __builtin_amdgcn_rcpf(s1.w));
    }

    // f1^T = Mem^T x am^T
    f32x4 C1[8];
    #pragma unroll
    for (int Mt = 0; Mt < 8; ++Mt) {
        short8 af = *(const short8*)(MemTf + (size_t)(Mt * 64 + l) * 8);
        f32x4 z = {0.f, 0.f, 0.f, 0.f};
        C1[Mt] = __builtin_amdgcn_mfma_f32_16x16x32_bf16(af, amf, z, 0, 0, 0);
    }

    // f2 = f1 * fe (fe gathered bf16 from ubW, 8-B loads)
    #pragma unroll
    for (int Mt = 0; Mt < 8; ++Mt) {
        uint2 fv = *(const uint2*)(fp3 + Mt * 16 + g * 4);
        float q0 = C1[Mt][0] * bf2f((short)(fv.x & 0xFFFF));
        float q1 = C1[Mt][1] * bf2f((short)(fv.x >> 16));
        float q2 = C1[Mt][2] * bf2f((short)(fv.y & 0xFFFF));
        float q3 = C1[Mt][3] * bf2f((short)(fv.y >> 16));
        unsigned d0 = ((unsigned)(unsigned short)f2bf(q0)) |
                      (((unsigned)(unsigned short)f2bf(q1)) << 16);
        unsigned d1 = ((unsigned)(unsigned short)f2bf(q2)) |
                      (((unsigned)(unsigned short)f2bf(q3)) << 16);
        int lane2 = ((Mt & 1) * 2 + (g >> 1)) * 16 + c;
        int off = ((Mt >> 1) * 64 + lane2) * 8 + (g & 1) * 4;
        uint2 dd = {d0, d1};
        *(uint2*)&f2s[w][off] = dd;
    }

    // h^T = WA^T x f2^T (+ iid row tile => y_f)
    f32x4 C2[4], C3 = {0.f, 0.f, 0.f, 0.f};
    #pragma unroll
    for (int Ma = 0; Ma < 4; ++Ma) C2[Ma] = (f32x4){0.f, 0.f, 0.f, 0.f};
    #pragma unroll
    for (int Kt = 0; Kt < 4; ++Kt) {
        short8 bf = *(const short8*)&f2s[w][(Kt * 64 + l) * 8];
        #pragma unroll
        for (int Ma = 0; Ma < 4; ++Ma) {
            short8 af = *(const short8*)(WATf + (size_t)((Ma * 4 + Kt) * 64 + l) * 8);
            C2[Ma] = __builtin_amdgcn_mfma_f32_16x16x32_bf16(af, bf, C2[Ma], 0, 0, 0);
        }
        short8 itf = {0, 0, 0, 0, 0, 0, 0, 0};
        if (c == 0) {
            float4 i0 = *(const float4*)&iidL[Kt * 32 + g * 8];
            float4 i1 = *(const float4*)&iidL[Kt * 32 + g * 8 + 4];
            itf[0] = f2bf(i0.x); itf[1] = f2bf(i0.y);
            itf[2] = f2bf(i0.z); itf[3] = f2bf(i0.w);
            itf[4] = f2bf(i1.x); itf[5] = f2bf(i1.y);
            itf[6] = f2bf(i1.z); itf[7] = f2bf(i1.w);
        }
        C3 = __builtin_amdgcn_mfma_f32_16x16x32_bf16(itf, bf, C3, 0, 0, 0);
    }

    float psum = 0.f;
    #pragma unroll
    for (int Ma = 0; Ma < 4; ++Ma) {
        float4 ba4 = *(const float4*)&baL[Ma * 16 + g * 4];
        float4 uo4 = *(const float4*)&uoL[Ma * 16 + g * 4];
        psum += fmaxf(C2[Ma][0] + ba4.x, 0.f) * uo4.x;
        psum += fmaxf(C2[Ma][1] + ba4.y, 0.f) * uo4.y;
        psum += fmaxf(C2[Ma][2] + ba4.z, 0.f) * uo4.z;
        psum += fmaxf(C2[Ma][3] + ba4.w, 0.f) * uo4.w;
    }
    psum += __shfl_xor(psum, 16, 64);
    psum += __shfl_xor(psum, 32, 64);
    const float jv = (fn > 0.f) ? __expf(psum) : 0.f;
    const float jy = jv * C3[0];
    float sj = waveReduceSum((g == 0) ? jv : 0.f);
    float sy = waveReduceSum(jy);
    if (l == 0) { sjW[w] = sj; syW[w] = sy; }
    __syncthreads();

    if (w == 0) {
        float s = uidL[l] * iidL[l] + uidL[l + 64] * iidL[l + 64];
        s = waveReduceSum(s);
        if (l == 0) {
            float Sj = sjW[0] + sjW[1] + sjW[2] + sjW[3] + 1e-8f;
            float Sy = syW[0] + syW[1] + syW[2] + syW[3];
            out[b] = s + Sy / Sj + i_bias[ii];
        }
    }
}

extern "C" void kernel_launch(void* const* d_in, const int* in_sizes, int n_in,
                              void* d_out, int out_size, void* d_ws, size_t ws_size,
                              hipStream_t stream)
{
    const int*   input_u  = (const int*)d_in[0];
    const int*   input_i  = (const int*)d_in[1];
    const int*   input_uf = (const int*)d_in[2];
    const float* uidW     = (const float*)d_in[3];
    const float* iidW     = (const float*)d_in[4];
    const float* i_bias   = (const float*)d_in[5];
    const float* Key      = (const float*)d_in[6];
    const float* Mem      = (const float*)d_in[7];
    const float* WA       = (const float*)d_in[8];
    const float* BA       = (const float*)d_in[9];
    const float* U_om     = (const float*)d_in[10];

    const int B = in_sizes[0];
    const int nU = in_sizes[3];              // (USER_NUM+1)*128 floats
    const int user_num = nU / EDIM - 1;

    float* eatt = (float*)d_ws;                      // B*400 floats
    float* S    = eatt + (size_t)B * NCOL;           // 400 floats
    short* WATf  = (short*)(S + NCOL);               // 16*64*8
    short* MemTf = WATf + 16 * 64 * 8;               // 8*64*8
    short* KeyTf = MemTf + 8 * 64 * 8;               // 4*64*8
    short* ubW   = KeyTf + 4 * 64 * 8;               // nU bf16 (25.6 MB)

    const int cvtBlocks = (nU / 8 + 255) / 256;
    k0_all<<<cvtBlocks + 9, 256, 0, stream>>>(uidW, WA, Mem, Key,
                                              ubW, WATf, MemTf, KeyTf, S,
                                              nU, cvtBlocks);
    k1_attkey<<<B, 256, 0, stream>>>(input_u, input_uf, ubW, KeyTf, eatt, user_num);
    k2a_sum<<<NPART, 256, 0, stream>>>(eatt, S, B);
    k3_final<<<B, 256, 0, stream>>>(input_u, input_i, input_uf, uidW, iidW, i_bias,
                                    WATf, MemTf, BA, U_om, eatt, S, ubW,
                                    (float*)d_out, user_num);
}